// Round 1
// baseline (477.629 us; speedup 1.0000x reference)
//
#include <hip/hip_runtime.h>
#include <stdint.h>

#define A_TOTAL 129600   // 9*120*120 anchors per batch
#define NBATCH 8
#define PRE 3000
#define POST 300
#define NWORD 47         // ceil(3000/64)

__device__ __forceinline__ unsigned xform(float f) {
    unsigned b = __float_as_uint(f);
    return (b & 0x80000000u) ? ~b : (b | 0x80000000u);  // monotonic float->uint
}

// ---------------- top-k (radix select + bitonic sort), one block per batch ----------------
__global__ __launch_bounds__(1024) void topk_kernel(const float* __restrict__ cls,
                                                    int* __restrict__ order,
                                                    float* __restrict__ tscores) {
    const int n = blockIdx.x;
    const int tid = threadIdx.x;
    const int bs = blockDim.x;  // 1024
    const float* sc = cls + (size_t)n * A_TOTAL;

    __shared__ unsigned hist[256];
    __shared__ unsigned sel_b, sel_rem, cnt;
    __shared__ unsigned long long keys[4096];

    unsigned mask_hi = 0u, prefix = 0u;
    unsigned kneed = PRE;
    for (int pass = 0; pass < 4; ++pass) {
        int shift = 24 - 8 * pass;
        for (int b = tid; b < 256; b += bs) hist[b] = 0u;
        __syncthreads();
        for (int i = tid; i < A_TOTAL; i += bs) {
            unsigned u = xform(sc[i]);
            if ((u & mask_hi) == prefix) atomicAdd(&hist[(u >> shift) & 255u], 1u);
        }
        __syncthreads();
        if (tid == 0) {
            unsigned acc = 0u; int b = 255;
            for (; b > 0; --b) {
                if (acc + hist[b] >= kneed) break;
                acc += hist[b];
            }
            sel_b = (unsigned)b;
            sel_rem = kneed - acc;
        }
        __syncthreads();
        prefix |= sel_b << shift;
        mask_hi |= 0xFFu << shift;
        kneed = sel_rem;
        __syncthreads();
    }
    // prefix == transformed value of the PRE-th largest score

    if (tid == 0) cnt = 0u;
    for (int i = tid; i < 4096; i += bs) keys[i] = ~0ull;
    __syncthreads();
    for (int i = tid; i < A_TOTAL; i += bs) {
        unsigned u = xform(sc[i]);
        if (u >= prefix) {
            unsigned slot = atomicAdd(&cnt, 1u);
            if (slot < 4096u)
                keys[slot] = ((unsigned long long)(~u) << 32) | (unsigned)i;
        }
    }
    __syncthreads();

    // bitonic sort ascending on 4096 keys: (~u desc-score, idx asc) packed
    for (int k = 2; k <= 4096; k <<= 1) {
        for (int j = k >> 1; j > 0; j >>= 1) {
            for (int i = tid; i < 4096; i += bs) {
                int ixj = i ^ j;
                if (ixj > i) {
                    unsigned long long a = keys[i], b = keys[ixj];
                    bool up = ((i & k) == 0);
                    if ((a > b) == up) { keys[i] = b; keys[ixj] = a; }
                }
            }
            __syncthreads();
        }
    }

    for (int t = tid; t < PRE; t += bs) {
        unsigned idx = (unsigned)keys[t];
        order[n * PRE + t] = (int)idx;
        tscores[n * PRE + t] = sc[idx];  // exact original value
    }
}

// ---------------- gather scrambled boxes for selected indices ----------------
__global__ void gather_kernel(const float* __restrict__ bbox,
                              const int* __restrict__ order,
                              float* __restrict__ boxes) {
    int g = blockIdx.x * blockDim.x + threadIdx.x;
    if (g >= NBATCH * PRE) return;
    int n = g / PRE;
    int r = order[g];          // region row index (numerically same as score index)
    int kp = r % 9;            // k'
    int pp = r / 9;            // h'*120 + w'
    int s_ch = pp % 36;        // source channel (depends on output spatial pos only!)
    int qbase = pp / 36;
    int k2 = s_ch >> 2, j2 = s_ch & 3;

    float ratio = (k2 < 3) ? 0.5f : ((k2 < 6) ? 1.0f : 2.0f);
    int si = k2 % 3;
    float scale = (si == 0) ? 8.0f : ((si == 1) ? 16.0f : 32.0f);
    float sq = sqrtf(ratio);
    float wsk = 16.0f * scale / sq;
    float hsk = 16.0f * scale * sq;

    float* outp = boxes + (size_t)g * 4;
#pragma unroll
    for (int j = 0; j < 4; ++j) {
        int c = 4 * kp + j;
        int q = c * 400 + qbase;       // source spatial h*120+w
        int h = q / 120, w2 = q % 120;
        float cx = (w2 + 0.5f) * 16.0f;
        float cy = (h + 0.5f) * 16.0f;
        float a;
        if (j2 == 0)      a = cx - 0.5f * wsk;
        else if (j2 == 1) a = cy - 0.5f * hsk;
        else if (j2 == 2) a = cx + 0.5f * wsk;
        else              a = cy + 0.5f * hsk;
        float d = bbox[((size_t)n * 36 + s_ch) * 14400 + q];
        outp[j] = fminf(fmaxf(a + d, 0.0f), 1919.0f);
    }
}

// ---------------- IoU suppression bitmask, 64x64 tiles ----------------
__global__ void nms_mask_kernel(const float* __restrict__ boxes,
                                unsigned long long* __restrict__ mask) {
    int cb = blockIdx.x, rb = blockIdx.y, n = blockIdx.z;
    int t = threadIdx.x;
    __shared__ float cx1[64], cy1[64], cx2[64], cy2[64], car[64];
    int cj = cb * 64 + t;
    if (cj < PRE) {
        const float* bp = boxes + ((size_t)n * PRE + cj) * 4;
        float x1 = bp[0], y1 = bp[1], x2 = bp[2], y2 = bp[3];
        cx1[t] = x1; cy1[t] = y1; cx2[t] = x2; cy2[t] = y2;
        car[t] = (x2 - x1 + 1.0f) * (y2 - y1 + 1.0f);
    }
    __syncthreads();
    int i = rb * 64 + t;
    if (i >= PRE) return;
    const float* bp = boxes + ((size_t)n * PRE + i) * 4;
    float x1 = bp[0], y1 = bp[1], x2 = bp[2], y2 = bp[3];
    float ai = (x2 - x1 + 1.0f) * (y2 - y1 + 1.0f);
    unsigned long long w = 0ull;
    int lim = min(64, PRE - cb * 64);
    for (int jj = 0; jj < lim; ++jj) {
        float xx1 = fmaxf(x1, cx1[jj]);
        float yy1 = fmaxf(y1, cy1[jj]);
        float xx2 = fminf(x2, cx2[jj]);
        float yy2 = fminf(y2, cy2[jj]);
        float iw = fmaxf(xx2 - xx1 + 1.0f, 0.0f);
        float ih = fmaxf(yy2 - yy1 + 1.0f, 0.0f);
        float inter = iw * ih;
        float iou = inter / (ai + car[jj] - inter);
        if (iou > 0.5f) w |= (1ull << jj);
    }
    mask[((size_t)n * PRE + i) * NWORD + cb] = w;
}

// ---------------- sequential greedy scan, one wave per batch ----------------
__global__ __launch_bounds__(64) void nms_scan_kernel(const unsigned long long* __restrict__ mask,
                                                      const float* __restrict__ tscores,
                                                      const float* __restrict__ boxes,
                                                      float* __restrict__ kept_scores,
                                                      float* __restrict__ kept_boxes) {
    int n = blockIdx.x;
    int lane = threadIdx.x;
    __shared__ int kidx[POST];
    unsigned long long rem = 0ull;
    int cnt = 0;
    const unsigned long long* mrow = mask + (size_t)n * PRE * NWORD;
    for (int i = 0; i < PRE; ++i) {
        int wi = i >> 6, bi = i & 63;
        unsigned long long rw = __shfl(rem, wi);
        if (!((rw >> bi) & 1ull)) {
            if (lane == 0) kidx[cnt] = i;
            cnt++;
            if (cnt >= POST) break;
            if (lane < NWORD) rem |= mrow[(size_t)i * NWORD + lane];
        }
    }
    __syncthreads();
    for (int t = lane; t < POST; t += 64) {
        if (t < cnt) {
            int i = kidx[t];
            kept_scores[n * POST + t] = tscores[n * PRE + i];
            const float* bp = boxes + ((size_t)n * PRE + i) * 4;
            float* kp = kept_boxes + ((size_t)n * POST + t) * 4;
            kp[0] = bp[0]; kp[1] = bp[1]; kp[2] = bp[2]; kp[3] = bp[3];
        } else {
            kept_scores[n * POST + t] = 0.0f;
            float* kp = kept_boxes + ((size_t)n * POST + t) * 4;
            kp[0] = 0.0f; kp[1] = 0.0f; kp[2] = 0.0f; kp[3] = 0.0f;
        }
    }
}

// ---------------- final assembly: (8,300,5), score col = batch 7 ----------------
__global__ void assemble_kernel(const float* __restrict__ kept_scores,
                                const float* __restrict__ kept_boxes,
                                float* __restrict__ out) {
    int g = blockIdx.x * blockDim.x + threadIdx.x;
    if (g >= NBATCH * POST * 5) return;
    int n = g / (POST * 5);
    int rr = g % (POST * 5);
    int t = rr / 5;
    int c = rr % 5;
    out[g] = (c == 0) ? kept_scores[(NBATCH - 1) * POST + t]
                      : kept_boxes[((size_t)n * POST + t) * 4 + (c - 1)];
}

extern "C" void kernel_launch(void* const* d_in, const int* in_sizes, int n_in,
                              void* d_out, int out_size, void* d_ws, size_t ws_size,
                              hipStream_t stream) {
    const float* cls = (const float*)d_in[0];   // (8,9,120,120)
    const float* bbox = (const float*)d_in[1];  // (8,36,120,120)
    float* out = (float*)d_out;                 // (8,300,5)

    char* p = (char*)d_ws;
    unsigned long long* mask = (unsigned long long*)p;           p += (size_t)NBATCH * PRE * NWORD * 8;  // 9,024,000
    int* order = (int*)p;                                        p += (size_t)NBATCH * PRE * 4;
    float* tscores = (float*)p;                                  p += (size_t)NBATCH * PRE * 4;
    float* boxes = (float*)p;                                    p += (size_t)NBATCH * PRE * 4 * 4;
    float* kept_scores = (float*)p;                              p += (size_t)NBATCH * POST * 4;
    float* kept_boxes = (float*)p;                               p += (size_t)NBATCH * POST * 4 * 4;
    (void)ws_size; (void)n_in; (void)in_sizes; (void)out_size;

    topk_kernel<<<NBATCH, 1024, 0, stream>>>(cls, order, tscores);
    gather_kernel<<<(NBATCH * PRE + 255) / 256, 256, 0, stream>>>(bbox, order, boxes);
    nms_mask_kernel<<<dim3(NWORD, NWORD, NBATCH), 64, 0, stream>>>(boxes, mask);
    nms_scan_kernel<<<NBATCH, 64, 0, stream>>>(mask, tscores, boxes, kept_scores, kept_boxes);
    assemble_kernel<<<(NBATCH * POST * 5 + 255) / 256, 256, 0, stream>>>(kept_scores, kept_boxes, out);
}

// Round 2
// 349.012 us; speedup vs baseline: 1.3685x; 1.3685x over previous
//
#include <hip/hip_runtime.h>
#include <stdint.h>

#define A_TOTAL 129600   // 9*120*120 anchors per batch
#define NBATCH 8
#define PRE 3000
#define POST 300
#define NWORD 47         // ceil(3000/64)
#define CAP 4096         // candidate buffer per batch (>= PRE + ties)
#define NTILE 1128       // 47*48/2 upper-triangle tiles

typedef unsigned long long u64;

__device__ __forceinline__ unsigned xform(float f) {
    unsigned b = __float_as_uint(f);
    return (b & 0x80000000u) ? ~b : (b | 0x80000000u);  // monotonic float->uint
}
__device__ __forceinline__ float unxform(unsigned u) {
    return __uint_as_float((u & 0x80000000u) ? (u & 0x7FFFFFFFu) : ~u);
}

// ---------------- zero the global histogram ----------------
__global__ void zero_kernel(unsigned* __restrict__ ghist) {
    int g = blockIdx.x * blockDim.x + threadIdx.x;
    if (g < NBATCH * 4096) ghist[g] = 0u;
}

// ---------------- pass 1: 12-bit histogram (bits 20..31), wide grid ----------------
__global__ __launch_bounds__(256) void hist1_kernel(const float* __restrict__ cls,
                                                    unsigned* __restrict__ ghist) {
    const int n = blockIdx.y;
    __shared__ unsigned h[4096];
    for (int i = threadIdx.x; i < 4096; i += 256) h[i] = 0u;
    __syncthreads();
    const float4* c4 = (const float4*)(cls + (size_t)n * A_TOTAL);
    const int n4 = A_TOTAL / 4;   // 32400
    for (int i = blockIdx.x * 256 + threadIdx.x; i < n4; i += gridDim.x * 256) {
        float4 v = c4[i];
        atomicAdd(&h[xform(v.x) >> 20], 1u);
        atomicAdd(&h[xform(v.y) >> 20], 1u);
        atomicAdd(&h[xform(v.z) >> 20], 1u);
        atomicAdd(&h[xform(v.w) >> 20], 1u);
    }
    __syncthreads();
    unsigned* gh = ghist + n * 4096;
    for (int i = threadIdx.x; i < 4096; i += 256)
        if (h[i]) atomicAdd(&gh[i], h[i]);
}

// ---------------- pick bucket from pass-1 histogram ----------------
__global__ __launch_bounds__(256) void pick1_kernel(const unsigned* __restrict__ ghist,
                                                    unsigned* __restrict__ state) {
    const int n = blockIdx.x;
    const int tid = threadIdx.x;
    __shared__ unsigned gsum[256];
    const unsigned* gh = ghist + n * 4096;
    unsigned s = 0;
    for (int q = 0; q < 16; ++q) s += gh[tid * 16 + q];
    gsum[tid] = s;
    __syncthreads();
    if (tid == 0) {
        unsigned acc = 0; int g = 255;
        for (; g > 0; --g) { if (acc + gsum[g] >= PRE) break; acc += gsum[g]; }
        int b = 16 * g + 15;
        for (; b >= 16 * g; --b) { if (acc + gh[b] >= PRE) break; acc += gh[b]; }
        state[n * 4 + 0] = (unsigned)b;        // prefix12
        state[n * 4 + 1] = PRE - acc;          // kneed1
    }
}

// ---------------- resolve exact 32-bit threshold + compact candidates ----------------
__global__ __launch_bounds__(1024) void resolve_kernel(const float* __restrict__ cls,
                                                       const unsigned* __restrict__ state,
                                                       u64* __restrict__ cand,
                                                       int* __restrict__ ccount) {
    const int n = blockIdx.x;
    const int tid = threadIdx.x;
    __shared__ unsigned h[4096];
    __shared__ unsigned gsum[256];
    __shared__ unsigned s_p12, s_k1, s_p24, s_k2, s_uT, s_cnt;
    if (tid == 0) { s_p12 = state[n * 4 + 0]; s_k1 = state[n * 4 + 1]; }
    for (int i = tid; i < 4096; i += 1024) h[i] = 0u;
    __syncthreads();
    const float4* c4 = (const float4*)(cls + (size_t)n * A_TOTAL);
    const int n4 = A_TOTAL / 4;
    const unsigned p12 = s_p12;
    // scan 1: bits 8..19 among prefix12 matches
    for (int i = tid; i < n4; i += 1024) {
        float4 v = c4[i];
        unsigned u;
        u = xform(v.x); if ((u >> 20) == p12) atomicAdd(&h[(u >> 8) & 0xFFFu], 1u);
        u = xform(v.y); if ((u >> 20) == p12) atomicAdd(&h[(u >> 8) & 0xFFFu], 1u);
        u = xform(v.z); if ((u >> 20) == p12) atomicAdd(&h[(u >> 8) & 0xFFFu], 1u);
        u = xform(v.w); if ((u >> 20) == p12) atomicAdd(&h[(u >> 8) & 0xFFFu], 1u);
    }
    __syncthreads();
    if (tid < 256) {
        unsigned s = 0;
        for (int q = 0; q < 16; ++q) s += h[tid * 16 + q];
        gsum[tid] = s;
    }
    __syncthreads();
    if (tid == 0) {
        unsigned kneed = s_k1, acc = 0; int g = 255;
        for (; g > 0; --g) { if (acc + gsum[g] >= kneed) break; acc += gsum[g]; }
        int b = 16 * g + 15;
        for (; b >= 16 * g; --b) { if (acc + h[b] >= kneed) break; acc += h[b]; }
        s_p24 = (s_p12 << 12) | (unsigned)b;
        s_k2 = kneed - acc;
    }
    __syncthreads();
    const unsigned p24 = s_p24;
    for (int i = tid; i < 256; i += 1024) h[i] = 0u;
    __syncthreads();
    // scan 2: bits 0..7 among prefix24 matches
    for (int i = tid; i < n4; i += 1024) {
        float4 v = c4[i];
        unsigned u;
        u = xform(v.x); if ((u >> 8) == p24) atomicAdd(&h[u & 0xFFu], 1u);
        u = xform(v.y); if ((u >> 8) == p24) atomicAdd(&h[u & 0xFFu], 1u);
        u = xform(v.z); if ((u >> 8) == p24) atomicAdd(&h[u & 0xFFu], 1u);
        u = xform(v.w); if ((u >> 8) == p24) atomicAdd(&h[u & 0xFFu], 1u);
    }
    __syncthreads();
    if (tid == 0) {
        unsigned kneed = s_k2, acc = 0; int b = 255;
        for (; b >= 0; --b) { if (acc + h[b] >= kneed) break; acc += h[b]; }
        s_uT = (p24 << 8) | (unsigned)b;
        s_cnt = 0;
    }
    __syncthreads();
    const unsigned uT = s_uT;
    // scan 3: compact all u >= uT as keys (u desc, idx asc via ~idx)
    u64* cd = cand + (size_t)n * CAP;
    for (int i = tid; i < n4; i += 1024) {
        float4 v = c4[i];
        const float* vf = (const float*)&v;
#pragma unroll
        for (int c = 0; c < 4; ++c) {
            unsigned u = xform(vf[c]);
            if (u >= uT) {
                unsigned slot = atomicAdd(&s_cnt, 1u);
                if (slot < CAP)
                    cd[slot] = ((u64)u << 32) | (unsigned)(~(4 * i + c));
            }
        }
    }
    __syncthreads();
    if (tid == 0) ccount[n] = (int)min(s_cnt, (unsigned)CAP);
}

// ---------------- rank-by-counting sort + fused box gather ----------------
__global__ __launch_bounds__(256) void ranksort_kernel(const u64* __restrict__ cand,
                                                       const int* __restrict__ ccount,
                                                       const float* __restrict__ bbox,
                                                       float* __restrict__ tscores,
                                                       float* __restrict__ boxes) {
    const int n = blockIdx.y;
    const int tid = threadIdx.x;
    __shared__ u64 k[CAP];
    const int C = min(ccount[n], CAP);
    const u64* cd = cand + (size_t)n * CAP;
    for (int i = tid; i < CAP; i += 256) k[i] = (i < C) ? cd[i] : 0ull;
    __syncthreads();
    const int i = blockIdx.x * 256 + tid;
    if (i >= C) return;
    const u64 key = k[i];
    int rank = 0;
    for (int j = 0; j < C; ++j) rank += (k[j] > key) ? 1 : 0;
    if (rank >= PRE) return;
    const unsigned u = (unsigned)(key >> 32);
    const int r = (int)(~(unsigned)key);     // original flat index
    tscores[n * PRE + rank] = unxform(u);

    // scrambled box gather (replicates reference reshape bug exactly)
    int kp = r % 9;            // k'
    int pp = r / 9;            // h'*120 + w'
    int s_ch = pp % 36;        // source channel
    int qbase = pp / 36;
    int k2 = s_ch >> 2, j2 = s_ch & 3;
    float ratio = (k2 < 3) ? 0.5f : ((k2 < 6) ? 1.0f : 2.0f);
    int si = k2 % 3;
    float scale = (si == 0) ? 8.0f : ((si == 1) ? 16.0f : 32.0f);
    float sq = sqrtf(ratio);
    float wsk = 16.0f * scale / sq;
    float hsk = 16.0f * scale * sq;
    float* outp = boxes + ((size_t)n * PRE + rank) * 4;
#pragma unroll
    for (int j = 0; j < 4; ++j) {
        int c = 4 * kp + j;
        int q = c * 400 + qbase;       // source spatial h*120+w
        int hh = q / 120, w2 = q % 120;
        float cx = (w2 + 0.5f) * 16.0f;
        float cy = (hh + 0.5f) * 16.0f;
        float a;
        if (j2 == 0)      a = cx - 0.5f * wsk;
        else if (j2 == 1) a = cy - 0.5f * hsk;
        else if (j2 == 2) a = cx + 0.5f * wsk;
        else              a = cy + 0.5f * hsk;
        float d = bbox[((size_t)n * 36 + s_ch) * 14400 + q];
        outp[j] = fminf(fmaxf(a + d, 0.0f), 1919.0f);
    }
}

// ---------------- IoU suppression bitmask, upper-triangle 64x64 tiles ----------------
__global__ __launch_bounds__(64) void nms_mask_kernel(const float* __restrict__ boxes,
                                                      u64* __restrict__ mask) {
    const int n = blockIdx.y;
    int T = blockIdx.x;
    int rb = 0, off = 0;
    for (int r = 0; r < NWORD; ++r) {
        int row_tiles = NWORD - r;
        if (T < off + row_tiles) { rb = r; break; }
        off += row_tiles;
    }
    const int cb = rb + (T - off);
    const int t = threadIdx.x;
    __shared__ float cx1[64], cy1[64], cx2[64], cy2[64], car[64];
    int cj = cb * 64 + t;
    if (cj < PRE) {
        const float* bp = boxes + ((size_t)n * PRE + cj) * 4;
        float x1 = bp[0], y1 = bp[1], x2 = bp[2], y2 = bp[3];
        cx1[t] = x1; cy1[t] = y1; cx2[t] = x2; cy2[t] = y2;
        car[t] = (x2 - x1 + 1.0f) * (y2 - y1 + 1.0f);
    }
    __syncthreads();
    int i = rb * 64 + t;
    if (i >= PRE) return;
    const float* bp = boxes + ((size_t)n * PRE + i) * 4;
    float x1 = bp[0], y1 = bp[1], x2 = bp[2], y2 = bp[3];
    float ai = (x2 - x1 + 1.0f) * (y2 - y1 + 1.0f);
    u64 w = 0ull;
    int lim = min(64, PRE - cb * 64);
    for (int jj = 0; jj < lim; ++jj) {
        float xx1 = fmaxf(x1, cx1[jj]);
        float yy1 = fmaxf(y1, cy1[jj]);
        float xx2 = fminf(x2, cx2[jj]);
        float yy2 = fminf(y2, cy2[jj]);
        float iw = fmaxf(xx2 - xx1 + 1.0f, 0.0f);
        float ih = fmaxf(yy2 - yy1 + 1.0f, 0.0f);
        float inter = iw * ih;
        float iou = inter / (ai + car[jj] - inter);
        if (iou > 0.5f) w |= (1ull << jj);
    }
    mask[((size_t)n * PRE + i) * NWORD + cb] = w;
}

// ---------------- window-serial greedy scan, one wave per batch ----------------
__global__ __launch_bounds__(64) void nms_scan_kernel(const u64* __restrict__ mask,
                                                      const float* __restrict__ tscores,
                                                      const float* __restrict__ boxes,
                                                      float* __restrict__ kept_scores,
                                                      float* __restrict__ out) {
    const int n = blockIdx.x;
    const int lane = threadIdx.x;
    __shared__ int kidx[POST];
    const u64* mrow = mask + (size_t)n * PRE * NWORD;
    u64 rem = 0ull;   // lane w holds suppression word w
    int cnt = 0;
    for (int w = 0; w < NWORD && cnt < POST; ++w) {
        const int base = 64 * w;
        const int lim = min(64, PRE - base);
        // lane b preloads row (base+b)'s word w (diagonal tile word)
        u64 vrow = (lane < lim) ? mrow[(size_t)(base + lane) * NWORD + w] : 0ull;
        unsigned cur_lo = (unsigned)__builtin_amdgcn_readlane((int)(unsigned)rem, w);
        unsigned cur_hi = (unsigned)__builtin_amdgcn_readlane((int)(unsigned)(rem >> 32), w);
        u64 cur = ((u64)cur_hi << 32) | cur_lo;
        u64 alive = 0ull;
        for (int b = 0; b < lim; ++b) {
            if (!((cur >> b) & 1ull)) {
                if (lane == 0) kidx[cnt] = base + b;
                cnt++;
                if (cnt >= POST) break;
                unsigned rl = (unsigned)__builtin_amdgcn_readlane((int)(unsigned)vrow, b);
                unsigned rh = (unsigned)__builtin_amdgcn_readlane((int)(unsigned)(vrow >> 32), b);
                cur |= ((u64)rh << 32) | rl;
                alive |= 1ull << b;
            }
        }
        // bulk cross-window update: independent loads, latency-overlapped
        while (alive) {
            int b = __ffsll((long long)alive) - 1;
            alive &= alive - 1;
            if (lane < NWORD) rem |= mrow[(size_t)(base + b) * NWORD + lane];
        }
    }
    __syncthreads();
    for (int t = lane; t < POST; t += 64) {
        float* op = out + ((size_t)n * POST + t) * 5;
        if (t < cnt) {
            int i = kidx[t];
            kept_scores[n * POST + t] = tscores[n * PRE + i];
            const float* bp = boxes + ((size_t)n * PRE + i) * 4;
            op[1] = bp[0]; op[2] = bp[1]; op[3] = bp[2]; op[4] = bp[3];
        } else {
            kept_scores[n * POST + t] = 0.0f;
            op[1] = 0.0f; op[2] = 0.0f; op[3] = 0.0f; op[4] = 0.0f;
        }
    }
}

// ---------------- score column: batch 7's kept scores broadcast ----------------
__global__ void scorecol_kernel(const float* __restrict__ kept_scores,
                                float* __restrict__ out) {
    int g = blockIdx.x * blockDim.x + threadIdx.x;
    if (g >= NBATCH * POST) return;
    int t = g % POST;
    out[(size_t)g * 5] = kept_scores[(NBATCH - 1) * POST + t];
}

extern "C" void kernel_launch(void* const* d_in, const int* in_sizes, int n_in,
                              void* d_out, int out_size, void* d_ws, size_t ws_size,
                              hipStream_t stream) {
    const float* cls = (const float*)d_in[0];   // (8,9,120,120)
    const float* bbox = (const float*)d_in[1];  // (8,36,120,120)
    float* out = (float*)d_out;                 // (8,300,5)

    char* p = (char*)d_ws;
    // Overlay region: ghist/state/ccount/cand are dead before mask is written
    // (stream-ordered), so they share the mask's 9,024,000-byte region.
    u64* mask = (u64*)p;                               // 8*3000*47*8 = 9,024,000
    unsigned* ghist = (unsigned*)p;                    // 131,072
    unsigned* state = (unsigned*)(p + 131072);         // 128
    int* ccount = (int*)(p + 131200);                  // 32
    u64* cand = (u64*)(p + 131584);                    // 8*4096*8 = 262,144 (ends 393,728)
    float* tscores = (float*)(p + 9024000);            // 96,000
    float* boxes = (float*)(p + 9120000);              // 384,000
    float* kept_scores = (float*)(p + 9504000);        // 9,600  (total 9,513,600)
    (void)ws_size; (void)n_in; (void)in_sizes; (void)out_size;

    zero_kernel<<<(NBATCH * 4096 + 255) / 256, 256, 0, stream>>>(ghist);
    hist1_kernel<<<dim3(32, NBATCH), 256, 0, stream>>>(cls, ghist);
    pick1_kernel<<<NBATCH, 256, 0, stream>>>(ghist, state);
    resolve_kernel<<<NBATCH, 1024, 0, stream>>>(cls, state, cand, ccount);
    ranksort_kernel<<<dim3(CAP / 256, NBATCH), 256, 0, stream>>>(cand, ccount, bbox, tscores, boxes);
    nms_mask_kernel<<<dim3(NTILE, NBATCH), 64, 0, stream>>>(boxes, mask);
    nms_scan_kernel<<<NBATCH, 64, 0, stream>>>(mask, tscores, boxes, kept_scores, out);
    scorecol_kernel<<<(NBATCH * POST + 255) / 256, 256, 0, stream>>>(kept_scores, out);
}

// Round 3
// 230.436 us; speedup vs baseline: 2.0727x; 1.5146x over previous
//
#include <hip/hip_runtime.h>
#include <stdint.h>

#define A_TOTAL 129600   // 9*120*120 anchors per batch
#define NBATCH 8
#define PRE 3000
#define POST 300
#define NWORD 47         // ceil(3000/64)
#define CAP 6144         // candidate buffer per batch (top bucket adds ~900 over 3000)
#define NTILE 1128       // 47*48/2 upper-triangle tiles
#define HBLK 32          // wide-scan blocks per batch

typedef unsigned long long u64;

__device__ __forceinline__ unsigned xform(float f) {
    unsigned b = __float_as_uint(f);
    return (b & 0x80000000u) ? ~b : (b | 0x80000000u);  // monotonic float->uint
}
__device__ __forceinline__ float unxform(unsigned u) {
    return __uint_as_float((u & 0x80000000u) ? (u & 0x7FFFFFFFu) : ~u);
}
__device__ __forceinline__ u64 readlane64(u64 v, int l) {
    unsigned lo = (unsigned)__builtin_amdgcn_readlane((int)(unsigned)v, l);
    unsigned hi = (unsigned)__builtin_amdgcn_readlane((int)(unsigned)(v >> 32), l);
    return ((u64)hi << 32) | lo;
}

// ---------------- zero histograms + counters ----------------
__global__ void zero_kernel(unsigned* __restrict__ ghist, int* __restrict__ ccount) {
    int g = blockIdx.x * blockDim.x + threadIdx.x;
    if (g < NBATCH * 4096) ghist[g] = 0u;
    else if (g < NBATCH * 4096 + NBATCH) ccount[g - NBATCH * 4096] = 0;
}

// ---------------- wide 12-bit histogram (bits 20..31) ----------------
__global__ __launch_bounds__(256) void hist1_kernel(const float* __restrict__ cls,
                                                    unsigned* __restrict__ ghist) {
    const int n = blockIdx.y;
    __shared__ unsigned h[4096];
    for (int i = threadIdx.x; i < 4096; i += 256) h[i] = 0u;
    __syncthreads();
    const float4* c4 = (const float4*)(cls + (size_t)n * A_TOTAL);
    const int n4 = A_TOTAL / 4;   // 32400
    for (int i = blockIdx.x * 256 + threadIdx.x; i < n4; i += HBLK * 256) {
        float4 v = c4[i];
        atomicAdd(&h[xform(v.x) >> 20], 1u);
        atomicAdd(&h[xform(v.y) >> 20], 1u);
        atomicAdd(&h[xform(v.z) >> 20], 1u);
        atomicAdd(&h[xform(v.w) >> 20], 1u);
    }
    __syncthreads();
    unsigned* gh = ghist + n * 4096;
    for (int i = threadIdx.x; i < 4096; i += 256)
        if (h[i]) atomicAdd(&gh[i], h[i]);
}

// ---------------- pick coarse bucket: uT = b<<20 s.t. count(u >= uT) >= PRE ----------------
__global__ __launch_bounds__(256) void pick1_kernel(const unsigned* __restrict__ ghist,
                                                    unsigned* __restrict__ state) {
    const int n = blockIdx.x;
    const int tid = threadIdx.x;
    __shared__ unsigned gsum[256];
    const unsigned* gh = ghist + n * 4096;
    unsigned s = 0;
    for (int q = 0; q < 16; ++q) s += gh[tid * 16 + q];
    gsum[tid] = s;
    __syncthreads();
    if (tid == 0) {
        unsigned acc = 0; int g = 255;
        for (; g > 0; --g) { if (acc + gsum[g] >= PRE) break; acc += gsum[g]; }
        int b = 16 * g + 15;
        for (; b >= 16 * g; --b) { if (acc + gh[b] >= PRE) break; acc += gh[b]; }
        state[n] = ((unsigned)b) << 20;        // coarse threshold
    }
}

// ---------------- wide compaction of all u >= uT (order irrelevant) ----------------
__global__ __launch_bounds__(256) void compact_kernel(const float* __restrict__ cls,
                                                      const unsigned* __restrict__ state,
                                                      u64* __restrict__ cand,
                                                      int* __restrict__ ccount) {
    const int n = blockIdx.y;
    const int tid = threadIdx.x;
    __shared__ u64 lbuf[4096];
    __shared__ unsigned lcnt, lbase;
    if (tid == 0) lcnt = 0u;
    __syncthreads();
    const unsigned uT = state[n];
    const float4* c4 = (const float4*)(cls + (size_t)n * A_TOTAL);
    const int n4 = A_TOTAL / 4;
    for (int i = blockIdx.x * 256 + tid; i < n4; i += HBLK * 256) {
        float4 v = c4[i];
        const float* vf = (const float*)&v;
#pragma unroll
        for (int c = 0; c < 4; ++c) {
            unsigned u = xform(vf[c]);
            if (u >= uT) {
                unsigned slot = atomicAdd(&lcnt, 1u);
                if (slot < 4096u)
                    lbuf[slot] = ((u64)u << 32) | (unsigned)(~(4 * i + c));
            }
        }
    }
    __syncthreads();
    if (tid == 0) lbase = (unsigned)atomicAdd(&ccount[n], (int)min(lcnt, 4096u));
    __syncthreads();
    const unsigned cnt = min(lcnt, 4096u), base = lbase;
    u64* cd = cand + (size_t)n * CAP;
    for (unsigned j = tid; j < cnt; j += 256)
        if (base + j < CAP) cd[base + j] = lbuf[j];
}

// ---------------- rank-by-counting sort + fused box gather ----------------
__global__ __launch_bounds__(256) void ranksort_kernel(const u64* __restrict__ cand,
                                                       const int* __restrict__ ccount,
                                                       const float* __restrict__ bbox,
                                                       float* __restrict__ tscores,
                                                       float* __restrict__ boxes) {
    const int n = blockIdx.y;
    const int tid = threadIdx.x;
    const int C = min(ccount[n], CAP);
    if (blockIdx.x * 256 >= C) return;
    __shared__ u64 k[CAP];
    const u64* cd = cand + (size_t)n * CAP;
    for (int i = tid; i < C; i += 256) k[i] = cd[i];
    __syncthreads();
    const int i = blockIdx.x * 256 + tid;
    if (i >= C) return;
    const u64 key = k[i];
    int rank = 0;
    int j = 0;
    for (; j + 8 <= C; j += 8) {
        rank += (k[j] > key) + (k[j+1] > key) + (k[j+2] > key) + (k[j+3] > key)
              + (k[j+4] > key) + (k[j+5] > key) + (k[j+6] > key) + (k[j+7] > key);
    }
    for (; j < C; ++j) rank += (k[j] > key) ? 1 : 0;
    if (rank >= PRE) return;
    const unsigned u = (unsigned)(key >> 32);
    const int r = (int)(~(unsigned)key);     // original flat index
    tscores[n * PRE + rank] = unxform(u);

    // scrambled box gather (replicates reference reshape bug exactly)
    int kp = r % 9;            // k'
    int pp = r / 9;            // h'*120 + w'
    int s_ch = pp % 36;        // source channel
    int qbase = pp / 36;
    int k2 = s_ch >> 2, j2 = s_ch & 3;
    float ratio = (k2 < 3) ? 0.5f : ((k2 < 6) ? 1.0f : 2.0f);
    int si = k2 % 3;
    float scale = (si == 0) ? 8.0f : ((si == 1) ? 16.0f : 32.0f);
    float sq = sqrtf(ratio);
    float wsk = 16.0f * scale / sq;
    float hsk = 16.0f * scale * sq;
    float* outp = boxes + ((size_t)n * PRE + rank) * 4;
#pragma unroll
    for (int j4 = 0; j4 < 4; ++j4) {
        int c = 4 * kp + j4;
        int q = c * 400 + qbase;       // source spatial h*120+w
        int hh = q / 120, w2 = q % 120;
        float cx = (w2 + 0.5f) * 16.0f;
        float cy = (hh + 0.5f) * 16.0f;
        float a;
        if (j2 == 0)      a = cx - 0.5f * wsk;
        else if (j2 == 1) a = cy - 0.5f * hsk;
        else if (j2 == 2) a = cx + 0.5f * wsk;
        else              a = cy + 0.5f * hsk;
        float d = bbox[((size_t)n * 36 + s_ch) * 14400 + q];
        outp[j4] = fminf(fmaxf(a + d, 0.0f), 1919.0f);
    }
}

// ---------------- IoU bitmask, upper-triangle tiles, 4 tiles per block ----------------
__global__ __launch_bounds__(256) void nms_mask_kernel(const float* __restrict__ boxes,
                                                       u64* __restrict__ mask) {
    const int n = blockIdx.y;
    const int t = threadIdx.x & 63;
    const int wv = threadIdx.x >> 6;
    const int T = blockIdx.x * 4 + wv;
    const bool active = (T < NTILE);
    __shared__ float cx1[4][64], cy1[4][64], cx2[4][64], cy2[4][64], car[4][64];
    int rb = 0, cb = 0;
    if (active) {
        int off = 0;
        for (int r = 0; r < NWORD; ++r) {
            int row_tiles = NWORD - r;
            if (T < off + row_tiles) { rb = r; cb = r + (T - off); break; }
            off += row_tiles;
        }
        int cj = cb * 64 + t;
        if (cj < PRE) {
            float4 b4 = *(const float4*)(boxes + ((size_t)n * PRE + cj) * 4);
            cx1[wv][t] = b4.x; cy1[wv][t] = b4.y; cx2[wv][t] = b4.z; cy2[wv][t] = b4.w;
            car[wv][t] = (b4.z - b4.x + 1.0f) * (b4.w - b4.y + 1.0f);
        }
    }
    __syncthreads();
    if (!active) return;
    int i = rb * 64 + t;
    if (i >= PRE) return;
    float4 b4 = *(const float4*)(boxes + ((size_t)n * PRE + i) * 4);
    float x1 = b4.x, y1 = b4.y, x2 = b4.z, y2 = b4.w;
    float ai = (x2 - x1 + 1.0f) * (y2 - y1 + 1.0f);
    u64 w = 0ull;
    int lim = min(64, PRE - cb * 64);
    for (int jj = 0; jj < lim; ++jj) {
        float xx1 = fmaxf(x1, cx1[wv][jj]);
        float yy1 = fmaxf(y1, cy1[wv][jj]);
        float xx2 = fminf(x2, cx2[wv][jj]);
        float yy2 = fminf(y2, cy2[wv][jj]);
        float iw = fmaxf(xx2 - xx1 + 1.0f, 0.0f);
        float ih = fmaxf(yy2 - yy1 + 1.0f, 0.0f);
        float inter = iw * ih;
        float iou = inter / (ai + car[wv][jj] - inter);
        if (iou > 0.5f) w |= (1ull << jj);
    }
    mask[((size_t)n * PRE + i) * NWORD + cb] = w;
}

// ---------------- greedy scan: LDS window tiles, double-buffered prefetch ----------------
// Wave 0 scans window w from LDS while waves 1..3 prefetch window w+1 from global.
#define TSTRIDE 49   // u64 stride: breaks bank aliasing on column reads
__global__ __launch_bounds__(256) void nms_scan_kernel(const u64* __restrict__ mask,
                                                       const float* __restrict__ tscores,
                                                       const float* __restrict__ boxes,
                                                       float* __restrict__ kept_scores,
                                                       float* __restrict__ out) {
    const int n = blockIdx.x;
    const int tid = threadIdx.x;
    const int lane = tid & 63;
    const int wv = tid >> 6;
    __shared__ u64 tile[2][64 * TSTRIDE];   // 2 * 24.5 KB
    __shared__ int kidx[POST];
    __shared__ int s_cnt;
    const u64* mrow = mask + (size_t)n * PRE * NWORD;

    // prefetch window 0 (all threads)
    for (int idx = tid; idx < 64 * NWORD; idx += 256) {
        int r = idx / NWORD, wd = idx % NWORD;
        tile[0][r * TSTRIDE + wd] = mrow[(size_t)r * NWORD + wd];  // rows 0..63 < PRE
    }
    if (tid == 0) s_cnt = 0;
    __syncthreads();

    u64 rem = 0ull;   // wave 0: lane l holds suppression word l
    for (int w = 0; w < NWORD; ++w) {
        const int buf = w & 1;
        if (wv > 0 && w + 1 < NWORD) {           // prefetch next window
            const int base = 64 * (w + 1);
            for (int idx = tid - 64; idx < 64 * NWORD; idx += 192) {
                int r = idx / NWORD, wd = idx % NWORD;
                int row = base + r;
                tile[buf ^ 1][r * TSTRIDE + wd] =
                    (row < PRE) ? mrow[(size_t)row * NWORD + wd] : 0ull;
            }
        }
        if (wv == 0) {
            int cnt = s_cnt;                      // uniform
            const int base = 64 * w;
            const int lim = min(64, PRE - base);
            u64 vrow = (lane < lim) ? tile[buf][lane * TSTRIDE + w] : 0ull;
            u64 cur = readlane64(rem, w);
            u64 alive = 0ull;
            for (int b = 0; b < lim; ++b) {
                if (!((cur >> b) & 1ull)) {
                    if (lane == 0) kidx[cnt] = base + b;
                    cnt++;
                    alive |= 1ull << b;
                    if (cnt >= POST) break;
                    cur |= readlane64(vrow, b);
                }
            }
            // cross-window rem updates from LDS, 4 outstanding reads
            if (lane < NWORD) {
                u64 t2 = alive;
                while (t2) {
                    int b0 = __ffsll((long long)t2) - 1; t2 &= t2 - 1;
                    int b1 = b0, b2 = b0, b3 = b0;
                    if (t2) { b1 = __ffsll((long long)t2) - 1; t2 &= t2 - 1; }
                    if (t2) { b2 = __ffsll((long long)t2) - 1; t2 &= t2 - 1; }
                    if (t2) { b3 = __ffsll((long long)t2) - 1; t2 &= t2 - 1; }
                    u64 a0 = tile[buf][b0 * TSTRIDE + lane];
                    u64 a1 = tile[buf][b1 * TSTRIDE + lane];
                    u64 a2 = tile[buf][b2 * TSTRIDE + lane];
                    u64 a3 = tile[buf][b3 * TSTRIDE + lane];
                    rem |= (a0 | a1) | (a2 | a3);
                }
            }
            if (lane == 0) s_cnt = cnt;
        }
        __syncthreads();
        if (s_cnt >= POST) break;
    }

    const int cnt = s_cnt;
    for (int t = tid; t < POST; t += 256) {
        float* op = out + ((size_t)n * POST + t) * 5;
        if (t < cnt) {
            int i = kidx[t];
            kept_scores[n * POST + t] = tscores[n * PRE + i];
            const float* bp = boxes + ((size_t)n * PRE + i) * 4;
            op[1] = bp[0]; op[2] = bp[1]; op[3] = bp[2]; op[4] = bp[3];
        } else {
            kept_scores[n * POST + t] = 0.0f;
            op[1] = 0.0f; op[2] = 0.0f; op[3] = 0.0f; op[4] = 0.0f;
        }
    }
}

// ---------------- score column: batch 7's kept scores broadcast ----------------
__global__ void scorecol_kernel(const float* __restrict__ kept_scores,
                                float* __restrict__ out) {
    int g = blockIdx.x * blockDim.x + threadIdx.x;
    if (g >= NBATCH * POST) return;
    int t = g % POST;
    out[(size_t)g * 5] = kept_scores[(NBATCH - 1) * POST + t];
}

extern "C" void kernel_launch(void* const* d_in, const int* in_sizes, int n_in,
                              void* d_out, int out_size, void* d_ws, size_t ws_size,
                              hipStream_t stream) {
    const float* cls = (const float*)d_in[0];   // (8,9,120,120)
    const float* bbox = (const float*)d_in[1];  // (8,36,120,120)
    float* out = (float*)d_out;                 // (8,300,5)

    char* p = (char*)d_ws;
    // Overlay: ghist/state/ccount/cand are dead before mask is written (stream order).
    u64* mask = (u64*)p;                               // 8*3000*47*8 = 9,024,000
    unsigned* ghist = (unsigned*)p;                    // 131,072
    unsigned* state = (unsigned*)(p + 131072);         // 32
    int* ccount = (int*)(p + 131200);                  // 32
    u64* cand = (u64*)(p + 131584);                    // 8*6144*8 = 393,216 (ends 524,800)
    float* tscores = (float*)(p + 9024000);            // 96,000
    float* boxes = (float*)(p + 9120000);              // 384,000
    float* kept_scores = (float*)(p + 9504000);        // 9,600  (total 9,513,600)
    (void)ws_size; (void)n_in; (void)in_sizes; (void)out_size;

    zero_kernel<<<(NBATCH * 4096 + NBATCH + 255) / 256, 256, 0, stream>>>(ghist, ccount);
    hist1_kernel<<<dim3(HBLK, NBATCH), 256, 0, stream>>>(cls, ghist);
    pick1_kernel<<<NBATCH, 256, 0, stream>>>(ghist, state);
    compact_kernel<<<dim3(HBLK, NBATCH), 256, 0, stream>>>(cls, state, cand, ccount);
    ranksort_kernel<<<dim3(CAP / 256, NBATCH), 256, 0, stream>>>(cand, ccount, bbox, tscores, boxes);
    nms_mask_kernel<<<dim3((NTILE + 3) / 4, NBATCH), 256, 0, stream>>>(boxes, mask);
    nms_scan_kernel<<<NBATCH, 256, 0, stream>>>(mask, tscores, boxes, kept_scores, out);
    scorecol_kernel<<<(NBATCH * POST + 255) / 256, 256, 0, stream>>>(kept_scores, out);
}

// Round 4
// 188.052 us; speedup vs baseline: 2.5399x; 1.2254x over previous
//
#include <hip/hip_runtime.h>
#include <stdint.h>

#define A_TOTAL 129600   // 9*120*120 anchors per batch
#define NBATCH 8
#define PRE 3000
#define POST 300
#define NWORD 47         // ceil(3000/64)
#define CAP 6144         // candidate buffer per batch (top bucket adds ~1700 over 3000 worst case)
#define NTILE 1128       // 47*48/2 upper-triangle tiles
#define HBLK 32          // wide-scan blocks per batch
#define JCHUNK 768       // ranksort j-chunk (CAP/JCHUNK = 8 chunks)

typedef unsigned long long u64;

__device__ __forceinline__ unsigned xform(float f) {
    unsigned b = __float_as_uint(f);
    return (b & 0x80000000u) ? ~b : (b | 0x80000000u);  // monotonic float->uint
}
__device__ __forceinline__ float unxform(unsigned u) {
    return __uint_as_float((u & 0x80000000u) ? (u & 0x7FFFFFFFu) : ~u);
}
__device__ __forceinline__ u64 readlane64(u64 v, int l) {
    unsigned lo = (unsigned)__builtin_amdgcn_readlane((int)(unsigned)v, l);
    unsigned hi = (unsigned)__builtin_amdgcn_readlane((int)(unsigned)(v >> 32), l);
    return ((u64)hi << 32) | lo;
}

// ---------------- zero histograms + counters + rank array ----------------
__global__ void zero_kernel(unsigned* __restrict__ ghist, int* __restrict__ ccount,
                            int* __restrict__ grank) {
    int g = blockIdx.x * blockDim.x + threadIdx.x;
    if (g < NBATCH * 4096) ghist[g] = 0u;
    else if (g < NBATCH * 4096 + NBATCH) ccount[g - NBATCH * 4096] = 0;
    else if (g < NBATCH * 4096 + NBATCH + NBATCH * CAP)
        grank[g - NBATCH * 4096 - NBATCH] = 0;
}

// ---------------- wide 12-bit histogram (bits 20..31) ----------------
__global__ __launch_bounds__(256) void hist1_kernel(const float* __restrict__ cls,
                                                    unsigned* __restrict__ ghist) {
    const int n = blockIdx.y;
    __shared__ unsigned h[4096];
    for (int i = threadIdx.x; i < 4096; i += 256) h[i] = 0u;
    __syncthreads();
    const float4* c4 = (const float4*)(cls + (size_t)n * A_TOTAL);
    const int n4 = A_TOTAL / 4;   // 32400
    for (int i = blockIdx.x * 256 + threadIdx.x; i < n4; i += HBLK * 256) {
        float4 v = c4[i];
        atomicAdd(&h[xform(v.x) >> 20], 1u);
        atomicAdd(&h[xform(v.y) >> 20], 1u);
        atomicAdd(&h[xform(v.z) >> 20], 1u);
        atomicAdd(&h[xform(v.w) >> 20], 1u);
    }
    __syncthreads();
    unsigned* gh = ghist + n * 4096;
    for (int i = threadIdx.x; i < 4096; i += 256)
        if (h[i]) atomicAdd(&gh[i], h[i]);
}

// ---------------- pick coarse bucket: uT = b<<20 s.t. count(u >= uT) >= PRE ----------------
__global__ __launch_bounds__(256) void pick1_kernel(const unsigned* __restrict__ ghist,
                                                    unsigned* __restrict__ state) {
    const int n = blockIdx.x;
    const int tid = threadIdx.x;
    __shared__ unsigned gsum[256];
    const unsigned* gh = ghist + n * 4096;
    unsigned s = 0;
    for (int q = 0; q < 16; ++q) s += gh[tid * 16 + q];
    gsum[tid] = s;
    __syncthreads();
    if (tid == 0) {
        unsigned acc = 0; int g = 255;
        for (; g > 0; --g) { if (acc + gsum[g] >= PRE) break; acc += gsum[g]; }
        int b = 16 * g + 15;
        for (; b >= 16 * g; --b) { if (acc + gh[b] >= PRE) break; acc += gh[b]; }
        state[n] = ((unsigned)b) << 20;        // coarse threshold
    }
}

// ---------------- wide compaction of all u >= uT (order irrelevant) ----------------
__global__ __launch_bounds__(256) void compact_kernel(const float* __restrict__ cls,
                                                      const unsigned* __restrict__ state,
                                                      u64* __restrict__ cand,
                                                      int* __restrict__ ccount) {
    const int n = blockIdx.y;
    const int tid = threadIdx.x;
    __shared__ u64 lbuf[4096];
    __shared__ unsigned lcnt, lbase;
    if (tid == 0) lcnt = 0u;
    __syncthreads();
    const unsigned uT = state[n];
    const float4* c4 = (const float4*)(cls + (size_t)n * A_TOTAL);
    const int n4 = A_TOTAL / 4;
    for (int i = blockIdx.x * 256 + tid; i < n4; i += HBLK * 256) {
        float4 v = c4[i];
        const float* vf = (const float*)&v;
#pragma unroll
        for (int c = 0; c < 4; ++c) {
            unsigned u = xform(vf[c]);
            if (u >= uT) {
                unsigned slot = atomicAdd(&lcnt, 1u);
                if (slot < 4096u)
                    lbuf[slot] = ((u64)u << 32) | (unsigned)(~(4 * i + c));
            }
        }
    }
    __syncthreads();
    if (tid == 0) lbase = (unsigned)atomicAdd(&ccount[n], (int)min(lcnt, 4096u));
    __syncthreads();
    const unsigned cnt = min(lcnt, 4096u), base = lbase;
    u64* cd = cand + (size_t)n * CAP;
    for (unsigned j = tid; j < cnt; j += 256)
        if (base + j < CAP) cd[base + j] = lbuf[j];
}

// ---------------- partial rank-by-counting: j-dimension split across blocks ----------------
__global__ __launch_bounds__(256) void ranksort_partial(const u64* __restrict__ cand,
                                                        const int* __restrict__ ccount,
                                                        int* __restrict__ grank) {
    const int n = blockIdx.z;
    const int C = min(ccount[n], CAP);
    if (blockIdx.x * 256 >= C) return;
    const int j0 = blockIdx.y * JCHUNK;
    if (j0 >= C) return;
    const int tid = threadIdx.x;
    __shared__ u64 k[JCHUNK];
    const u64* cd = cand + (size_t)n * CAP;
    const int jlim = min(JCHUNK, C - j0);
    for (int j = tid; j < JCHUNK; j += 256)
        k[j] = (j < jlim) ? cd[j0 + j] : 0ull;   // 0 never > any real key
    __syncthreads();
    const int i = blockIdx.x * 256 + tid;
    if (i >= C) return;
    const u64 key = cd[i];
    int rank = 0;
    int j = 0;
    for (; j + 8 <= JCHUNK; j += 8) {
        rank += (k[j] > key) + (k[j+1] > key) + (k[j+2] > key) + (k[j+3] > key)
              + (k[j+4] > key) + (k[j+5] > key) + (k[j+6] > key) + (k[j+7] > key);
    }
    if (rank) atomicAdd(&grank[n * CAP + i], rank);
}

// ---------------- gather: rank -> ordered scores + scrambled box gather ----------------
__global__ __launch_bounds__(256) void rank_gather(const u64* __restrict__ cand,
                                                   const int* __restrict__ ccount,
                                                   const int* __restrict__ grank,
                                                   const float* __restrict__ bbox,
                                                   float* __restrict__ tscores,
                                                   float* __restrict__ boxes) {
    const int n = blockIdx.y;
    const int C = min(ccount[n], CAP);
    const int i = blockIdx.x * 256 + threadIdx.x;
    if (i >= C) return;
    const int rank = grank[n * CAP + i];
    if (rank >= PRE) return;
    const u64 key = cand[(size_t)n * CAP + i];
    const unsigned u = (unsigned)(key >> 32);
    const int r = (int)(~(unsigned)key);     // original flat index
    tscores[n * PRE + rank] = unxform(u);

    // scrambled box gather (replicates reference reshape bug exactly)
    int kp = r % 9;            // k'
    int pp = r / 9;            // h'*120 + w'
    int s_ch = pp % 36;        // source channel
    int qbase = pp / 36;
    int k2 = s_ch >> 2, j2 = s_ch & 3;
    float ratio = (k2 < 3) ? 0.5f : ((k2 < 6) ? 1.0f : 2.0f);
    int si = k2 % 3;
    float scale = (si == 0) ? 8.0f : ((si == 1) ? 16.0f : 32.0f);
    float sq = sqrtf(ratio);
    float wsk = 16.0f * scale / sq;
    float hsk = 16.0f * scale * sq;
    float* outp = boxes + ((size_t)n * PRE + rank) * 4;
#pragma unroll
    for (int j4 = 0; j4 < 4; ++j4) {
        int c = 4 * kp + j4;
        int q = c * 400 + qbase;       // source spatial h*120+w
        int hh = q / 120, w2 = q % 120;
        float cx = (w2 + 0.5f) * 16.0f;
        float cy = (hh + 0.5f) * 16.0f;
        float a;
        if (j2 == 0)      a = cx - 0.5f * wsk;
        else if (j2 == 1) a = cy - 0.5f * hsk;
        else if (j2 == 2) a = cx + 0.5f * wsk;
        else              a = cy + 0.5f * hsk;
        float d = bbox[((size_t)n * 36 + s_ch) * 14400 + q];
        outp[j4] = fminf(fmaxf(a + d, 0.0f), 1919.0f);
    }
}

// ---------------- IoU bitmask, upper-triangle tiles, 4 tiles per block ----------------
__global__ __launch_bounds__(256) void nms_mask_kernel(const float* __restrict__ boxes,
                                                       u64* __restrict__ mask) {
    const int n = blockIdx.y;
    const int t = threadIdx.x & 63;
    const int wv = threadIdx.x >> 6;
    const int T = blockIdx.x * 4 + wv;
    const bool active = (T < NTILE);
    __shared__ float cx1[4][64], cy1[4][64], cx2[4][64], cy2[4][64], car[4][64];
    int rb = 0, cb = 0;
    if (active) {
        int off = 0;
        for (int r = 0; r < NWORD; ++r) {
            int row_tiles = NWORD - r;
            if (T < off + row_tiles) { rb = r; cb = r + (T - off); break; }
            off += row_tiles;
        }
        int cj = cb * 64 + t;
        if (cj < PRE) {
            float4 b4 = *(const float4*)(boxes + ((size_t)n * PRE + cj) * 4);
            cx1[wv][t] = b4.x; cy1[wv][t] = b4.y; cx2[wv][t] = b4.z; cy2[wv][t] = b4.w;
            car[wv][t] = (b4.z - b4.x + 1.0f) * (b4.w - b4.y + 1.0f);
        }
    }
    __syncthreads();
    if (!active) return;
    int i = rb * 64 + t;
    if (i >= PRE) return;
    float4 b4 = *(const float4*)(boxes + ((size_t)n * PRE + i) * 4);
    float x1 = b4.x, y1 = b4.y, x2 = b4.z, y2 = b4.w;
    float ai = (x2 - x1 + 1.0f) * (y2 - y1 + 1.0f);
    u64 w = 0ull;
    int lim = min(64, PRE - cb * 64);
    for (int jj = 0; jj < lim; ++jj) {
        float xx1 = fmaxf(x1, cx1[wv][jj]);
        float yy1 = fmaxf(y1, cy1[wv][jj]);
        float xx2 = fminf(x2, cx2[wv][jj]);
        float yy2 = fminf(y2, cy2[wv][jj]);
        float iw = fmaxf(xx2 - xx1 + 1.0f, 0.0f);
        float ih = fmaxf(yy2 - yy1 + 1.0f, 0.0f);
        float inter = iw * ih;
        float iou = inter / (ai + car[wv][jj] - inter);
        if (iou > 0.5f) w |= (1ull << jj);
    }
    mask[((size_t)n * PRE + i) * NWORD + cb] = w;
}

// ---------------- greedy scan: LDS window tiles, double-buffered prefetch ----------------
#define TSTRIDE 49   // u64 stride: breaks bank aliasing on column reads
__global__ __launch_bounds__(256) void nms_scan_kernel(const u64* __restrict__ mask,
                                                       const float* __restrict__ tscores,
                                                       const float* __restrict__ boxes,
                                                       float* __restrict__ kept_scores,
                                                       float* __restrict__ out) {
    const int n = blockIdx.x;
    const int tid = threadIdx.x;
    const int lane = tid & 63;
    const int wv = tid >> 6;
    __shared__ u64 tile[2][64 * TSTRIDE];   // 2 * 24.5 KB
    __shared__ int kidx[POST];
    __shared__ int s_cnt;
    const u64* mrow = mask + (size_t)n * PRE * NWORD;

    // prefetch window 0 (all threads)
    for (int idx = tid; idx < 64 * NWORD; idx += 256) {
        int r = idx / NWORD, wd = idx % NWORD;
        tile[0][r * TSTRIDE + wd] = mrow[(size_t)r * NWORD + wd];  // rows 0..63 < PRE
    }
    if (tid == 0) s_cnt = 0;
    __syncthreads();

    u64 rem = 0ull;   // wave 0: lane l holds suppression word l
    for (int w = 0; w < NWORD; ++w) {
        const int buf = w & 1;
        if (wv > 0 && w + 1 < NWORD) {           // prefetch next window
            const int base = 64 * (w + 1);
            for (int idx = tid - 64; idx < 64 * NWORD; idx += 192) {
                int r = idx / NWORD, wd = idx % NWORD;
                int row = base + r;
                tile[buf ^ 1][r * TSTRIDE + wd] =
                    (row < PRE) ? mrow[(size_t)row * NWORD + wd] : 0ull;
            }
        }
        if (wv == 0) {
            int cnt = s_cnt;                      // uniform
            const int base = 64 * w;
            const int lim = min(64, PRE - base);
            u64 vrow = (lane < lim) ? tile[buf][lane * TSTRIDE + w] : 0ull;
            u64 cur = readlane64(rem, w);
            u64 alive = 0ull;
            for (int b = 0; b < lim; ++b) {
                if (!((cur >> b) & 1ull)) {
                    if (lane == 0) kidx[cnt] = base + b;
                    cnt++;
                    alive |= 1ull << b;
                    if (cnt >= POST) break;
                    cur |= readlane64(vrow, b);
                }
            }
            // cross-window rem updates from LDS, 4 outstanding reads
            if (lane < NWORD) {
                u64 t2 = alive;
                while (t2) {
                    int b0 = __ffsll((long long)t2) - 1; t2 &= t2 - 1;
                    int b1 = b0, b2 = b0, b3 = b0;
                    if (t2) { b1 = __ffsll((long long)t2) - 1; t2 &= t2 - 1; }
                    if (t2) { b2 = __ffsll((long long)t2) - 1; t2 &= t2 - 1; }
                    if (t2) { b3 = __ffsll((long long)t2) - 1; t2 &= t2 - 1; }
                    u64 a0 = tile[buf][b0 * TSTRIDE + lane];
                    u64 a1 = tile[buf][b1 * TSTRIDE + lane];
                    u64 a2 = tile[buf][b2 * TSTRIDE + lane];
                    u64 a3 = tile[buf][b3 * TSTRIDE + lane];
                    rem |= (a0 | a1) | (a2 | a3);
                }
            }
            if (lane == 0) s_cnt = cnt;
        }
        __syncthreads();
        if (s_cnt >= POST) break;
    }

    const int cnt = s_cnt;
    for (int t = tid; t < POST; t += 256) {
        float* op = out + ((size_t)n * POST + t) * 5;
        if (t < cnt) {
            int i = kidx[t];
            kept_scores[n * POST + t] = tscores[n * PRE + i];
            const float* bp = boxes + ((size_t)n * PRE + i) * 4;
            op[1] = bp[0]; op[2] = bp[1]; op[3] = bp[2]; op[4] = bp[3];
        } else {
            kept_scores[n * POST + t] = 0.0f;
            op[1] = 0.0f; op[2] = 0.0f; op[3] = 0.0f; op[4] = 0.0f;
        }
    }
}

// ---------------- score column: batch 7's kept scores broadcast ----------------
__global__ void scorecol_kernel(const float* __restrict__ kept_scores,
                                float* __restrict__ out) {
    int g = blockIdx.x * blockDim.x + threadIdx.x;
    if (g >= NBATCH * POST) return;
    int t = g % POST;
    out[(size_t)g * 5] = kept_scores[(NBATCH - 1) * POST + t];
}

extern "C" void kernel_launch(void* const* d_in, const int* in_sizes, int n_in,
                              void* d_out, int out_size, void* d_ws, size_t ws_size,
                              hipStream_t stream) {
    const float* cls = (const float*)d_in[0];   // (8,9,120,120)
    const float* bbox = (const float*)d_in[1];  // (8,36,120,120)
    float* out = (float*)d_out;                 // (8,300,5)

    char* p = (char*)d_ws;
    // Overlay: ghist/state/ccount/cand/grank are dead before mask is written (stream order).
    u64* mask = (u64*)p;                               // 8*3000*47*8 = 9,024,000
    unsigned* ghist = (unsigned*)p;                    // 131,072
    unsigned* state = (unsigned*)(p + 131072);         // 32
    int* ccount = (int*)(p + 131200);                  // 32
    u64* cand = (u64*)(p + 131584);                    // 8*6144*8 = 393,216 (ends 524,800)
    int* grank = (int*)(p + 524800);                   // 8*6144*4 = 196,608 (ends 721,408)
    float* tscores = (float*)(p + 9024000);            // 96,000
    float* boxes = (float*)(p + 9120000);              // 384,000
    float* kept_scores = (float*)(p + 9504000);        // 9,600  (total 9,513,600)
    (void)ws_size; (void)n_in; (void)in_sizes; (void)out_size;

    zero_kernel<<<(NBATCH * 4096 + NBATCH + NBATCH * CAP + 255) / 256, 256, 0, stream>>>(ghist, ccount, grank);
    hist1_kernel<<<dim3(HBLK, NBATCH), 256, 0, stream>>>(cls, ghist);
    pick1_kernel<<<NBATCH, 256, 0, stream>>>(ghist, state);
    compact_kernel<<<dim3(HBLK, NBATCH), 256, 0, stream>>>(cls, state, cand, ccount);
    ranksort_partial<<<dim3(CAP / 256, CAP / JCHUNK, NBATCH), 256, 0, stream>>>(cand, ccount, grank);
    rank_gather<<<dim3(CAP / 256, NBATCH), 256, 0, stream>>>(cand, ccount, grank, bbox, tscores, boxes);
    nms_mask_kernel<<<dim3((NTILE + 3) / 4, NBATCH), 256, 0, stream>>>(boxes, mask);
    nms_scan_kernel<<<NBATCH, 256, 0, stream>>>(mask, tscores, boxes, kept_scores, out);
    scorecol_kernel<<<(NBATCH * POST + 255) / 256, 256, 0, stream>>>(kept_scores, out);
}